// Round 1
// baseline (107.294 us; speedup 1.0000x reference)
//
#include <hip/hip_runtime.h>
#include <stdint.h>

typedef __attribute__((ext_vector_type(8))) short short8;
typedef __attribute__((ext_vector_type(4))) float float4_t;

#define N_PTS 1024
#define G_DIM 620
#define G_PAD 640
#define F_DIM 20
#define H_DIM 150
#define H_PAD 160
#define H_PAD2 192
#define K_WIN 128
#define OUT_C (K_WIN + 1)

__device__ __forceinline__ float bf2f(short u) {
  union { unsigned int i; float f; } x;
  x.i = ((unsigned int)(unsigned short)u) << 16;
  return x.f;
}
__device__ __forceinline__ short f2bf(float f) {
  union { float f; unsigned int i; } x; x.f = f;
  unsigned int u = x.i;
  u += 0x7FFFu + ((u >> 16) & 1u);   // round-to-nearest-even
  return (short)(u >> 16);
}

// ---------------------------------------------------------------------------
// prep_misc: build bf16 copies / transposes + dist-emb @ W1d
//   g_bf  [1024][640] bf16 (zero pad d>=620)
//   W1cT  [160][640]  bf16 : W1cT[h][d] = W1[(1240+d)*150 + h]
//   W2T   [160][192]  bf16 : W2T[m][k]  = W2[k*150 + m]
//   deW   [9][160]    f32  : dist_emb[b] @ W1[1860:1880]
// ---------------------------------------------------------------------------
__global__ void prep_misc(const float* __restrict__ g, const float* __restrict__ W1,
                          const float* __restrict__ W2, const float* __restrict__ dist_emb,
                          short* __restrict__ g_bf, short* __restrict__ W1cT,
                          short* __restrict__ W2T, float* __restrict__ deW) {
  const int total1 = N_PTS * G_PAD;   // 655360
  const int total2 = H_PAD * G_PAD;   // 102400
  const int total3 = H_PAD * H_PAD2;  // 30720
  const int total4 = 9 * H_PAD;       // 1440
  const int total = total1 + total2 + total3 + total4;
  for (int t = blockIdx.x * blockDim.x + threadIdx.x; t < total;
       t += gridDim.x * blockDim.x) {
    if (t < total1) {
      int n = t / G_PAD, d = t % G_PAD;
      g_bf[t] = (d < G_DIM) ? f2bf(g[n * G_DIM + d]) : (short)0;
    } else if (t < total1 + total2) {
      int q = t - total1;
      int h = q / G_PAD, d = q % G_PAD;
      W1cT[q] = (h < H_DIM && d < G_DIM) ? f2bf(W1[(2 * G_DIM + d) * H_DIM + h]) : (short)0;
    } else if (t < total1 + total2 + total3) {
      int q = t - total1 - total2;
      int m = q / H_PAD2, k = q % H_PAD2;
      W2T[q] = (m < H_DIM && k < H_DIM) ? f2bf(W2[k * H_DIM + m]) : (short)0;
    } else {
      int q = t - total1 - total2 - total3;
      int b = q / H_PAD, h = q % H_PAD;
      float acc = 0.f;
      if (h < H_DIM) {
        for (int f = 0; f < F_DIM; ++f)
          acc += dist_emb[b * F_DIM + f] * W1[(3 * G_DIM + f) * H_DIM + h];
      }
      deW[q] = acc;
    }
  }
}

// ---------------------------------------------------------------------------
// prep_uv: U[n][h] = g[n] @ W1[0:620,:] + b1 ; V[n][h] = g[n] @ W1[620:1240,:]
// f32, padded to 160 cols (zeros beyond 149). 4 rows per block, 320 threads.
// ---------------------------------------------------------------------------
__global__ __launch_bounds__(320) void prep_uv(const float* __restrict__ g,
                                               const float* __restrict__ W1,
                                               const float* __restrict__ b1,
                                               float* __restrict__ U, float* __restrict__ V) {
  __shared__ float gs[4][G_DIM];
  const int n0 = blockIdx.x * 4;
  for (int t = threadIdx.x; t < 4 * G_DIM; t += 320) {
    int r = t / G_DIM, d = t % G_DIM;
    gs[r][d] = g[(n0 + r) * G_DIM + d];
  }
  __syncthreads();
  const int t = threadIdx.x;
  const bool isU = (t < H_PAD);
  const int col = isU ? t : (t - H_PAD);       // 0..159
  float a0 = 0.f, a1 = 0.f, a2 = 0.f, a3 = 0.f;
  if (col < H_DIM) {
    const float* Wc = W1 + (isU ? 0 : G_DIM * H_DIM) + col;
    #pragma unroll 4
    for (int d = 0; d < G_DIM; ++d) {
      float w = Wc[d * H_DIM];
      a0 += gs[0][d] * w; a1 += gs[1][d] * w; a2 += gs[2][d] * w; a3 += gs[3][d] * w;
    }
    if (isU) { float bb = b1[col]; a0 += bb; a1 += bb; a2 += bb; a3 += bb; }
  }
  float* O = isU ? U : V;
  O[(n0 + 0) * H_PAD + col] = a0;
  O[(n0 + 1) * H_PAD + col] = a1;
  O[(n0 + 2) * H_PAD + col] = a2;
  O[(n0 + 3) * H_PAD + col] = a3;
}

// ---------------------------------------------------------------------------
// pair_main: one block per i. 256 threads = 4 waves (2M x 2N).
// Layer1: D[m][h] = (g_i .* g_j[m]) @ W1c  via MFMA 16x16x32 bf16, K=640/64-step
// Epi1:   h1 = relu(D + U[i] + V[j] + deW[bin])  -> bf16 LDS [3][128][64] swz
// Layer2: D2 = h1 @ W2 (K padded 192), Epi2: s = relu(D2+b2) @ W3
// out[i][m] = valid ? si[i]+si[j]+s+b3 : 0 ; out[i][128] = 0
// ---------------------------------------------------------------------------
__global__ __launch_bounds__(256, 2) void pair_main(
    const short* __restrict__ g_bf, const short* __restrict__ W1cT,
    const short* __restrict__ W2T, const float* __restrict__ U,
    const float* __restrict__ V, const float* __restrict__ deW,
    const float* __restrict__ si, const int* __restrict__ i1,
    const int* __restrict__ i2, const float* __restrict__ W3,
    const float* __restrict__ b2, const float* __restrict__ b3,
    float* __restrict__ out) {
  __shared__ __align__(16) short gi_s[G_PAD];               // 1280 B
  __shared__ __align__(16) short bufB[H_PAD * 64];          // 20480 B (B tiles, L1+L2)
  __shared__ __align__(16) short bufH[3 * K_WIN * 64];      // 49152 B (P aliases tile0; h1 after)
  __shared__ float sj_s[K_WIN];
  __shared__ int bin_s[K_WIN];
  __shared__ float s_buf[2][K_WIN];

  short* bufP = bufH;  // layer-1 A staging lives in bufH tile 0 (dead before h1 writes)

  const int i = blockIdx.x;
  const int tid = threadIdx.x;
  const int lane = tid & 63;
  const int wid = tid >> 6;
  const int wm = wid >> 1;   // 0..1 : M half
  const int wn = wid & 1;    // 0..1 : N half
  const int lo4 = lane & 15;
  const int hi2 = lane >> 4; // 0..3

  // ---- preamble: gi row (bf16), bins, si[j] ----
  if (tid < G_PAD / 8)
    ((short8*)gi_s)[tid] = ((const short8*)(g_bf + i * G_PAD))[tid];
  if (tid < K_WIN) {
    int jr = i - K_WIN + tid;
    int jc = jr < 0 ? 0 : jr;
    int d = i2[i] - i1[jc];
    int b = (d >= 1) + (d >= 2) + (d >= 3) + (d >= 4) +
            (d >= 8) + (d >= 16) + (d >= 32) + (d >= 64);
    bin_s[tid] = b;
    sj_s[tid] = si[jc];
  }
  __syncthreads();

  const float4_t fzero = {0.f, 0.f, 0.f, 0.f};
  float4_t acc[4][5];
  #pragma unroll
  for (int a = 0; a < 4; ++a)
    #pragma unroll
    for (int b = 0; b < 5; ++b) acc[a][b] = fzero;

  // ---- layer 1: 10 K-steps of 64 over padded G dim ----
  for (int step = 0; step < 10; ++step) {
    const int d0 = step * 64;
    // stage P = gj .* gi : 128 rows x 64 cols bf16, swizzled
    #pragma unroll
    for (int cc = 0; cc < 4; ++cc) {
      int c = tid + 256 * cc;            // 0..1023
      int row = c >> 3, cb = c & 7;
      int jr = i - K_WIN + row;
      int jc = jr < 0 ? 0 : jr;
      short8 gj = *((const short8*)(g_bf + jc * G_PAD + d0 + cb * 8));
      short8 gi = *((const short8*)(gi_s + d0 + cb * 8));
      short8 p;
      #pragma unroll
      for (int e = 0; e < 8; ++e) p[e] = f2bf(bf2f(gj[e]) * bf2f(gi[e]));
      int byte = row * 128 + ((cb * 16) ^ ((row & 7) << 4));
      *((short8*)((char*)bufP + byte)) = p;
    }
    // stage Bt = W1cT[:, d0:d0+64] : 160 rows x 64 cols, swizzled
    #pragma unroll
    for (int cc = 0; cc < 5; ++cc) {
      int c = tid + 256 * cc;            // 0..1279
      int row = c >> 3, cb = c & 7;
      short8 w = *((const short8*)(W1cT + row * G_PAD + d0 + cb * 8));
      int byte = row * 128 + ((cb * 16) ^ ((row & 7) << 4));
      *((short8*)((char*)bufB + byte)) = w;
    }
    __syncthreads();
    #pragma unroll
    for (int ks = 0; ks < 2; ++ks) {
      const int kb = ks * 64 + 16 * hi2;  // byte col of this lane's 8-elem chunk
      short8 af[4], bq[5];
      #pragma unroll
      for (int mt = 0; mt < 4; ++mt) {
        int row = wm * 64 + mt * 16 + lo4;
        af[mt] = *((const short8*)((const char*)bufP + row * 128 + (kb ^ ((row & 7) << 4))));
      }
      #pragma unroll
      for (int nt = 0; nt < 5; ++nt) {
        int row = wn * 80 + nt * 16 + lo4;
        bq[nt] = *((const short8*)((const char*)bufB + row * 128 + (kb ^ ((row & 7) << 4))));
      }
      #pragma unroll
      for (int mt = 0; mt < 4; ++mt)
        #pragma unroll
        for (int nt = 0; nt < 5; ++nt)
          acc[mt][nt] = __builtin_amdgcn_mfma_f32_16x16x32_bf16(af[mt], bq[nt], acc[mt][nt], 0, 0, 0);
    }
    __syncthreads();
  }

  // ---- epilogue 1: h1 = relu(acc + U[i] + V[j] + deW[bin]) -> bufH bf16 ----
  const float* Ui = U + i * H_PAD;
  #pragma unroll
  for (int mt = 0; mt < 4; ++mt) {
    #pragma unroll
    for (int r = 0; r < 4; ++r) {
      int m = wm * 64 + mt * 16 + hi2 * 4 + r;
      int jr = i - K_WIN + m;
      int jc = jr < 0 ? 0 : jr;
      const float* Vj = V + jc * H_PAD;
      const float* De = deW + bin_s[m] * H_PAD;
      #pragma unroll
      for (int nt = 0; nt < 5; ++nt) {
        int h = wn * 80 + nt * 16 + lo4;
        float val = acc[mt][nt][r] + Ui[h] + Vj[h] + De[h];
        val = (h < H_DIM) ? fmaxf(val, 0.f) : 0.f;
        int tile = h >> 6, hc = h & 63;
        int byte = tile * 16384 + m * 128 + ((hc * 2) ^ ((m & 7) << 4));
        *((short*)((char*)bufH + byte)) = f2bf(val);
      }
    }
  }
  // zero-fill bufH tile2 cols 32..63 (k = 160..191 padding for uniform layer-2 loop)
  {
    short8 z = {0, 0, 0, 0, 0, 0, 0, 0};
    for (int c = tid; c < 512; c += 256) {
      int row = c >> 2, cb = c & 3;
      int byte = 2 * 16384 + row * 128 + ((64 + cb * 16) ^ ((row & 7) << 4));
      *((short8*)((char*)bufH + byte)) = z;
    }
  }
  __syncthreads();

  // ---- layer 2: D2 = h1 @ W2 (K = 192, zero padded) ----
  float4_t acc2[4][5];
  #pragma unroll
  for (int a = 0; a < 4; ++a)
    #pragma unroll
    for (int b = 0; b < 5; ++b) acc2[a][b] = fzero;

  for (int t2 = 0; t2 < 3; ++t2) {
    #pragma unroll
    for (int cc = 0; cc < 5; ++cc) {
      int c = tid + 256 * cc;            // 0..1279
      int row = c >> 3, cb = c & 7;
      short8 w = *((const short8*)(W2T + row * H_PAD2 + t2 * 64 + cb * 8));
      int byte = row * 128 + ((cb * 16) ^ ((row & 7) << 4));
      *((short8*)((char*)bufB + byte)) = w;
    }
    __syncthreads();
    #pragma unroll
    for (int ks = 0; ks < 2; ++ks) {
      const int kb = ks * 64 + 16 * hi2;
      short8 af[4], bq[5];
      #pragma unroll
      for (int mt = 0; mt < 4; ++mt) {
        int row = wm * 64 + mt * 16 + lo4;
        af[mt] = *((const short8*)((const char*)bufH + t2 * 16384 + row * 128 + (kb ^ ((row & 7) << 4))));
      }
      #pragma unroll
      for (int nt = 0; nt < 5; ++nt) {
        int row = wn * 80 + nt * 16 + lo4;
        bq[nt] = *((const short8*)((const char*)bufB + row * 128 + (kb ^ ((row & 7) << 4))));
      }
      #pragma unroll
      for (int mt = 0; mt < 4; ++mt)
        #pragma unroll
        for (int nt = 0; nt < 5; ++nt)
          acc2[mt][nt] = __builtin_amdgcn_mfma_f32_16x16x32_bf16(af[mt], bq[nt], acc2[mt][nt], 0, 0, 0);
    }
    __syncthreads();
  }

  // ---- epilogue 2: s = relu(acc2 + b2) @ W3, reduce, emit output ----
  float sp[4][4];
  #pragma unroll
  for (int mt = 0; mt < 4; ++mt)
    #pragma unroll
    for (int r = 0; r < 4; ++r) sp[mt][r] = 0.f;

  #pragma unroll
  for (int nt = 0; nt < 5; ++nt) {
    int h = wn * 80 + nt * 16 + lo4;
    float w3 = (h < H_DIM) ? W3[h] : 0.f;
    float bb = (h < H_DIM) ? b2[h] : 0.f;
    #pragma unroll
    for (int mt = 0; mt < 4; ++mt)
      #pragma unroll
      for (int r = 0; r < 4; ++r) {
        float hv = fmaxf(acc2[mt][nt][r] + bb, 0.f);
        sp[mt][r] += hv * w3;
      }
  }
  #pragma unroll
  for (int mt = 0; mt < 4; ++mt)
    #pragma unroll
    for (int r = 0; r < 4; ++r) {
      float v = sp[mt][r];
      v += __shfl_xor(v, 1);
      v += __shfl_xor(v, 2);
      v += __shfl_xor(v, 4);
      v += __shfl_xor(v, 8);
      sp[mt][r] = v;
    }
  if (lo4 == 0) {
    #pragma unroll
    for (int mt = 0; mt < 4; ++mt)
      #pragma unroll
      for (int r = 0; r < 4; ++r) {
        int m = wm * 64 + mt * 16 + hi2 * 4 + r;
        s_buf[wn][m] = sp[mt][r];
      }
  }
  __syncthreads();

  if (tid < K_WIN) {
    int m = tid;
    int jr = i - K_WIN + m;
    float sij = si[i] + sj_s[m] + s_buf[0][m] + s_buf[1][m] + b3[0];
    out[i * OUT_C + m] = (jr >= 0) ? sij : 0.f;
  }
  if (tid == K_WIN) out[i * OUT_C + K_WIN] = 0.f;
}

// ---------------------------------------------------------------------------
extern "C" void kernel_launch(void* const* d_in, const int* in_sizes, int n_in,
                              void* d_out, int out_size, void* d_ws, size_t ws_size,
                              hipStream_t stream) {
  const float* g  = (const float*)d_in[0];
  const float* si = (const float*)d_in[1];
  const int*   i1 = (const int*)d_in[2];
  const int*   i2 = (const int*)d_in[3];
  const float* de = (const float*)d_in[4];
  const float* W1 = (const float*)d_in[5];
  const float* b1 = (const float*)d_in[6];
  const float* W2 = (const float*)d_in[7];
  const float* b2 = (const float*)d_in[8];
  const float* W3 = (const float*)d_in[9];
  const float* b3 = (const float*)d_in[10];
  float* out = (float*)d_out;

  char* ws = (char*)d_ws;
  short* g_bf = (short*)(ws);                 // 1,310,720 B
  short* W1cT = (short*)(ws + 1310720);       //   204,800 B
  short* W2T  = (short*)(ws + 1515520);       //    61,440 B
  float* U    = (float*)(ws + 1576960);       //   655,360 B
  float* V    = (float*)(ws + 2232320);       //   655,360 B
  float* deW  = (float*)(ws + 2887680);       //     5,760 B  (total ~2.9 MB)

  prep_misc<<<1024, 256, 0, stream>>>(g, W1, W2, de, g_bf, W1cT, W2T, deW);
  prep_uv<<<N_PTS / 4, 320, 0, stream>>>(g, W1, b1, U, V);
  pair_main<<<N_PTS, 256, 0, stream>>>(g_bf, W1cT, W2T, U, V, deW, si, i1, i2, W3, b2, b3, out);
}

// Round 2
// 80.257 us; speedup vs baseline: 1.3369x; 1.3369x over previous
//
#include <hip/hip_runtime.h>
#include <hip/hip_bf16.h>
#include <stdint.h>

typedef __attribute__((ext_vector_type(8))) short short8;
typedef __attribute__((ext_vector_type(4))) float float4_t;

#define N_PTS 1024
#define G_DIM 620
#define G_PAD 640
#define F_DIM 20
#define H_DIM 150
#define H_PAD 160
#define H_PAD2 192
#define K_WIN 128
#define OUT_C (K_WIN + 1)

__device__ __forceinline__ float bf2f(short u) {
  union { unsigned int i; float f; } x;
  x.i = ((unsigned int)(unsigned short)u) << 16;
  return x.f;
}
// prep-path conversion (manual RNE)
__device__ __forceinline__ short f2bf(float f) {
  union { float f; unsigned int i; } x; x.f = f;
  unsigned int u = x.i;
  u += 0x7FFFu + ((u >> 16) & 1u);
  return (short)(u >> 16);
}
// hot-path conversion via HW instruction
__device__ __forceinline__ short f2bf_hw(float f) {
  __hip_bfloat16 h = __float2bfloat16(f);
  union { __hip_bfloat16 h; short s; } u; u.h = h;
  return u.s;
}
// async global -> LDS, 16B per lane (dest = wave-uniform base + lane*16)
__device__ __forceinline__ void gload_lds16(const void* g, void* l) {
  __builtin_amdgcn_global_load_lds(
      (const __attribute__((address_space(1))) unsigned int*)g,
      (__attribute__((address_space(3))) unsigned int*)l, 16, 0, 0);
}

// ---------------------------------------------------------------------------
// prep_misc: bf16 copies / transposes + dist-emb @ W1d
//   g_bf  [1024][640] bf16 ; W1cT [160][640] bf16 (W1c^T) ; W2T [160][192]
//   deW   [9][160] f32     ; W1abT [320][640] bf16 (rows 0..159 = W1a^T,
//                                                   rows 160..319 = W1b^T)
// ---------------------------------------------------------------------------
__global__ void prep_misc(const float* __restrict__ g, const float* __restrict__ W1,
                          const float* __restrict__ W2, const float* __restrict__ dist_emb,
                          short* __restrict__ g_bf, short* __restrict__ W1cT,
                          short* __restrict__ W2T, float* __restrict__ deW,
                          short* __restrict__ W1abT) {
  const int T1 = N_PTS * G_PAD;     // 655360
  const int T2 = H_PAD * G_PAD;     // 102400
  const int T3 = H_PAD * H_PAD2;    // 30720
  const int T4 = 9 * H_PAD;         // 1440
  const int T5 = 2 * H_PAD * G_PAD; // 204800
  const int total = T1 + T2 + T3 + T4 + T5;
  for (int t = blockIdx.x * blockDim.x + threadIdx.x; t < total;
       t += gridDim.x * blockDim.x) {
    if (t < T1) {
      int n = t / G_PAD, d = t % G_PAD;
      g_bf[t] = (d < G_DIM) ? f2bf(g[n * G_DIM + d]) : (short)0;
    } else if (t < T1 + T2) {
      int q = t - T1;
      int h = q / G_PAD, d = q % G_PAD;
      W1cT[q] = (h < H_DIM && d < G_DIM) ? f2bf(W1[(2 * G_DIM + d) * H_DIM + h]) : (short)0;
    } else if (t < T1 + T2 + T3) {
      int q = t - T1 - T2;
      int m = q / H_PAD2, k = q % H_PAD2;
      W2T[q] = (m < H_DIM && k < H_DIM) ? f2bf(W2[k * H_DIM + m]) : (short)0;
    } else if (t < T1 + T2 + T3 + T4) {
      int q = t - T1 - T2 - T3;
      int b = q / H_PAD, h = q % H_PAD;
      float acc = 0.f;
      if (h < H_DIM) {
        for (int f = 0; f < F_DIM; ++f)
          acc += dist_emb[b * F_DIM + f] * W1[(3 * G_DIM + f) * H_DIM + h];
      }
      deW[q] = acc;
    } else {
      int q = t - T1 - T2 - T3 - T4;
      int h = q / G_PAD, d = q % G_PAD;   // h in 0..319
      short v = 0;
      if (d < G_DIM) {
        if (h < H_PAD) { if (h < H_DIM) v = f2bf(W1[d * H_DIM + h]); }
        else { int col = h - H_PAD; if (col < H_DIM) v = f2bf(W1[(G_DIM + d) * H_DIM + col]); }
      }
      W1abT[q] = v;
    }
  }
}

// ---------------------------------------------------------------------------
// prep_uv_mfma: U (y=0) / V (y=1) = g_bf @ W1{a,b} via MFMA.
// grid (16, 2): block = 64 rows x 160 cols, K=640 in 10 steps of 64.
// 4 waves = 2M x 2N, acc[2][5].
// ---------------------------------------------------------------------------
__global__ __launch_bounds__(256) void prep_uv_mfma(
    const short* __restrict__ g_bf, const short* __restrict__ W1abT,
    const float* __restrict__ b1, float* __restrict__ U, float* __restrict__ V) {
  __shared__ __align__(16) char sA[64 * 128];    // 8 KB swz
  __shared__ __align__(16) char sB[160 * 128];   // 20 KB swz
  const int m0 = blockIdx.x * 64;
  const int yb = blockIdx.y * H_PAD;
  const int tid = threadIdx.x, lane = tid & 63, wid = tid >> 6;
  const int wm = wid >> 1, wn = wid & 1;
  const int lo4 = lane & 15, hi2 = lane >> 4;
  const int l8 = lane >> 3, c8 = lane & 7;
  const int xe = (c8 ^ (l8 & 7)) * 8;  // pre-swizzled source chunk offset (elems)

  const float4_t fz = {0.f, 0.f, 0.f, 0.f};
  float4_t acc[2][5];
  #pragma unroll
  for (int a = 0; a < 2; ++a)
    #pragma unroll
    for (int b = 0; b < 5; ++b) acc[a][b] = fz;

  for (int step = 0; step < 10; ++step) {
    const int d0 = step * 64;
    #pragma unroll
    for (int cc = 0; cc < 2; ++cc) {
      int row = wid * 8 + cc * 32 + l8;
      gload_lds16(g_bf + (m0 + row) * G_PAD + d0 + xe, sA + (wid * 8 + cc * 32) * 128);
    }
    #pragma unroll
    for (int cc = 0; cc < 5; ++cc) {
      int row = wid * 8 + cc * 32 + l8;
      gload_lds16(W1abT + (yb + row) * G_PAD + d0 + xe, sB + (wid * 8 + cc * 32) * 128);
    }
    __syncthreads();
    #pragma unroll
    for (int ks = 0; ks < 2; ++ks) {
      const int kb = ks * 64 + 16 * hi2;
      short8 af[2], bq[5];
      #pragma unroll
      for (int mt = 0; mt < 2; ++mt) {
        int row = wm * 32 + mt * 16 + lo4;
        af[mt] = *((const short8*)(sA + row * 128 + (kb ^ ((row & 7) << 4))));
      }
      #pragma unroll
      for (int nt = 0; nt < 5; ++nt) {
        int row = wn * 80 + nt * 16 + lo4;
        bq[nt] = *((const short8*)(sB + row * 128 + (kb ^ ((row & 7) << 4))));
      }
      #pragma unroll
      for (int mt = 0; mt < 2; ++mt)
        #pragma unroll
        for (int nt = 0; nt < 5; ++nt)
          acc[mt][nt] = __builtin_amdgcn_mfma_f32_16x16x32_bf16(af[mt], bq[nt], acc[mt][nt], 0, 0, 0);
    }
    __syncthreads();
  }

  float* O = blockIdx.y ? V : U;
  const bool isU = (blockIdx.y == 0);
  #pragma unroll
  for (int mt = 0; mt < 2; ++mt)
    #pragma unroll
    for (int r = 0; r < 4; ++r) {
      int m = m0 + wm * 32 + mt * 16 + hi2 * 4 + r;
      #pragma unroll
      for (int nt = 0; nt < 5; ++nt) {
        int h = wn * 80 + nt * 16 + lo4;
        float v = acc[mt][nt][r];
        if (h < H_DIM) { if (isU) v += b1[h]; } else { v = 0.f; }
        O[m * H_PAD + h] = v;
      }
    }
}

// ---------------------------------------------------------------------------
// pair_main: one block per i. 4 waves (2M x 2N). Double-buffered layer-1.
// ---------------------------------------------------------------------------
__global__ __launch_bounds__(256, 2) void pair_main(
    const short* __restrict__ g_bf, const short* __restrict__ W1cT,
    const short* __restrict__ W2T, const float* __restrict__ U,
    const float* __restrict__ V, const float* __restrict__ deW,
    const float* __restrict__ si, const int* __restrict__ i1,
    const int* __restrict__ i2, const float* __restrict__ W3,
    const float* __restrict__ b2, const float* __restrict__ b3,
    float* __restrict__ out) {
  __shared__ __align__(16) char smem[73728];
  __shared__ __align__(16) short gi_s[G_PAD];
  __shared__ float sj_s[K_WIN];
  __shared__ int bin_s[K_WIN];
  __shared__ float s_buf[2][K_WIN];

  char* const P0 = smem;              // 16 KB
  char* const P1 = smem + 16384;      // 16 KB
  char* const B0 = smem + 32768;      // 20 KB
  char* const B1 = smem + 53248;      // 20 KB
  char* const Hb = smem;              // h1: 3 x 16 KB tiles (aliases P0,P1,B0)

  const int i = blockIdx.x;
  const int tid = threadIdx.x;
  const int lane = tid & 63;
  const int wid = tid >> 6;
  const int wm = wid >> 1, wn = wid & 1;
  const int lo4 = lane & 15, hi2 = lane >> 4;
  const int l8 = lane >> 3, c8 = lane & 7;
  const int xe = (c8 ^ (l8 & 7)) * 8;
  const int tc8 = tid & 7;

  // ---- preamble ----
  if (tid < G_PAD / 8)
    ((short8*)gi_s)[tid] = ((const short8*)(g_bf + i * G_PAD))[tid];
  if (tid < K_WIN) {
    int jr = i - K_WIN + tid, jc = jr < 0 ? 0 : jr;
    int d = i2[i] - i1[jc];
    bin_s[tid] = (d >= 1) + (d >= 2) + (d >= 3) + (d >= 4) +
                 (d >= 8) + (d >= 16) + (d >= 32) + (d >= 64);
    sj_s[tid] = si[jc];
  }
  __syncthreads();

  // ---- staging helpers ----
  auto stageB1f = [&](int step, char* B) {   // W1cT K-slice -> LDS direct
    const int d0 = step * 64;
    #pragma unroll
    for (int cc = 0; cc < 5; ++cc) {
      int row = wid * 8 + cc * 32 + l8;
      gload_lds16(W1cT + row * G_PAD + d0 + xe, B + (wid * 8 + cc * 32) * 128);
    }
  };
  auto loadA = [&](int step, short8* gjv, short8& gvv) {
    const int d0 = step * 64;
    gvv = *((const short8*)(gi_s + d0 + tc8 * 8));
    #pragma unroll
    for (int cc = 0; cc < 4; ++cc) {
      int c = tid + 256 * cc, row = c >> 3;
      int jr = i - K_WIN + row, jc = jr < 0 ? 0 : jr;
      gjv[cc] = *((const short8*)(g_bf + jc * G_PAD + d0 + tc8 * 8));
    }
  };
  auto writeP = [&](char* P, const short8* gjv, const short8& gvv) {
    #pragma unroll
    for (int cc = 0; cc < 4; ++cc) {
      int c = tid + 256 * cc, row = c >> 3;
      short8 p;
      #pragma unroll
      for (int e = 0; e < 8; ++e) p[e] = f2bf_hw(bf2f(gjv[cc][e]) * bf2f(gvv[e]));
      int byte = row * 128 + ((tc8 * 16) ^ ((row & 7) << 4));
      *((short8*)(P + byte)) = p;
    }
  };

  // ---- prologue: stage step 0 ----
  {
    short8 gjv[4], gvv;
    stageB1f(0, B0);
    loadA(0, gjv, gvv);
    writeP(P0, gjv, gvv);
  }

  const float4_t fz = {0.f, 0.f, 0.f, 0.f};
  float4_t acc[4][5];
  #pragma unroll
  for (int a = 0; a < 4; ++a)
    #pragma unroll
    for (int b = 0; b < 5; ++b) acc[a][b] = fz;

  // ---- layer 1: 10 K-steps, one barrier per step, dbuf ----
  for (int step = 0; step < 10; ++step) {
    char* Pc = (step & 1) ? P1 : P0;
    char* Bc = (step & 1) ? B1 : B0;
    char* Pn = (step & 1) ? P0 : P1;
    char* Bn = (step & 1) ? B0 : B1;
    __syncthreads();                    // buf[cur] staged, buf[next] free
    short8 gjv[4], gvv;
    if (step < 9) {
      stageB1f(step + 1, Bn);           // async LDS-direct, in flight across MFMA
      loadA(step + 1, gjv, gvv);        // global->reg issue-early
    }
    #pragma unroll
    for (int ks = 0; ks < 2; ++ks) {
      const int kb = ks * 64 + 16 * hi2;
      short8 af[4], bq[5];
      #pragma unroll
      for (int mt = 0; mt < 4; ++mt) {
        int row = wm * 64 + mt * 16 + lo4;
        af[mt] = *((const short8*)(Pc + row * 128 + (kb ^ ((row & 7) << 4))));
      }
      #pragma unroll
      for (int nt = 0; nt < 5; ++nt) {
        int row = wn * 80 + nt * 16 + lo4;
        bq[nt] = *((const short8*)(Bc + row * 128 + (kb ^ ((row & 7) << 4))));
      }
      #pragma unroll
      for (int mt = 0; mt < 4; ++mt)
        #pragma unroll
        for (int nt = 0; nt < 5; ++nt)
          acc[mt][nt] = __builtin_amdgcn_mfma_f32_16x16x32_bf16(af[mt], bq[nt], acc[mt][nt], 0, 0, 0);
    }
    if (step < 9) writeP(Pn, gjv, gvv); // convert+write-late (loads landed under MFMA)
  }
  __syncthreads();  // all layer-1 reads done before Hb overwrites P0/P1/B0

  // ---- epilogue 1: h1 = relu(acc + U[i] + V[j] + deW[bin]) -> Hb bf16 swz ----
  const float* Ui = U + i * H_PAD;
  #pragma unroll
  for (int mt = 0; mt < 4; ++mt) {
    #pragma unroll
    for (int r = 0; r < 4; ++r) {
      int m = wm * 64 + mt * 16 + hi2 * 4 + r;
      int jr = i - K_WIN + m, jc = jr < 0 ? 0 : jr;
      const float* Vj = V + jc * H_PAD;
      const float* De = deW + bin_s[m] * H_PAD;
      #pragma unroll
      for (int nt = 0; nt < 5; ++nt) {
        int h = wn * 80 + nt * 16 + lo4;
        float val = acc[mt][nt][r] + Ui[h] + Vj[h] + De[h];
        val = (h < H_DIM) ? fmaxf(val, 0.f) : 0.f;
        int tile = h >> 6, hc = h & 63;
        int byte = tile * 16384 + m * 128 + ((hc * 2) ^ ((m & 7) << 4));
        *((short*)(Hb + byte)) = f2bf_hw(val);
      }
    }
  }

  // ---- layer 2: D2 = h1 @ W2, K=160 (t2==2 covers cols 128..159 only) ----
  float4_t acc2[4][5];
  #pragma unroll
  for (int a = 0; a < 4; ++a)
    #pragma unroll
    for (int b = 0; b < 5; ++b) acc2[a][b] = fz;

  #pragma unroll
  for (int t2 = 0; t2 < 3; ++t2) {
    #pragma unroll
    for (int cc = 0; cc < 5; ++cc) {
      int row = wid * 8 + cc * 32 + l8;
      gload_lds16(W2T + row * H_PAD2 + t2 * 64 + xe, B1 + (wid * 8 + cc * 32) * 128);
    }
    __syncthreads();
    #pragma unroll
    for (int ks = 0; ks < 2; ++ks) {
      if (t2 == 2 && ks == 1) continue;
      const int kb = ks * 64 + 16 * hi2;
      short8 af[4], bq[5];
      #pragma unroll
      for (int mt = 0; mt < 4; ++mt) {
        int row = wm * 64 + mt * 16 + lo4;
        af[mt] = *((const short8*)(Hb + t2 * 16384 + row * 128 + (kb ^ ((row & 7) << 4))));
      }
      #pragma unroll
      for (int nt = 0; nt < 5; ++nt) {
        int row = wn * 80 + nt * 16 + lo4;
        bq[nt] = *((const short8*)(B1 + row * 128 + (kb ^ ((row & 7) << 4))));
      }
      #pragma unroll
      for (int mt = 0; mt < 4; ++mt)
        #pragma unroll
        for (int nt = 0; nt < 5; ++nt)
          acc2[mt][nt] = __builtin_amdgcn_mfma_f32_16x16x32_bf16(af[mt], bq[nt], acc2[mt][nt], 0, 0, 0);
    }
    __syncthreads();
  }

  // ---- epilogue 2: s = relu(acc2 + b2) @ W3, reduce, emit ----
  float sp[4][4];
  #pragma unroll
  for (int mt = 0; mt < 4; ++mt)
    #pragma unroll
    for (int r = 0; r < 4; ++r) sp[mt][r] = 0.f;

  #pragma unroll
  for (int nt = 0; nt < 5; ++nt) {
    int h = wn * 80 + nt * 16 + lo4;
    float w3 = (h < H_DIM) ? W3[h] : 0.f;
    float bb = (h < H_DIM) ? b2[h] : 0.f;
    #pragma unroll
    for (int mt = 0; mt < 4; ++mt)
      #pragma unroll
      for (int r = 0; r < 4; ++r) {
        float hv = fmaxf(acc2[mt][nt][r] + bb, 0.f);
        sp[mt][r] += hv * w3;
      }
  }
  #pragma unroll
  for (int mt = 0; mt < 4; ++mt)
    #pragma unroll
    for (int r = 0; r < 4; ++r) {
      float v = sp[mt][r];
      v += __shfl_xor(v, 1);
      v += __shfl_xor(v, 2);
      v += __shfl_xor(v, 4);
      v += __shfl_xor(v, 8);
      sp[mt][r] = v;
    }
  if (lo4 == 0) {
    #pragma unroll
    for (int mt = 0; mt < 4; ++mt)
      #pragma unroll
      for (int r = 0; r < 4; ++r) {
        int m = wm * 64 + mt * 16 + hi2 * 4 + r;
        s_buf[wn][m] = sp[mt][r];
      }
  }
  __syncthreads();

  if (tid < K_WIN) {
    int m = tid;
    int jr = i - K_WIN + m;
    float sij = si[i] + sj_s[m] + s_buf[0][m] + s_buf[1][m] + b3[0];
    out[i * OUT_C + m] = (jr >= 0) ? sij : 0.f;
  }
  if (tid == K_WIN) out[i * OUT_C + K_WIN] = 0.f;
}

// ---------------------------------------------------------------------------
extern "C" void kernel_launch(void* const* d_in, const int* in_sizes, int n_in,
                              void* d_out, int out_size, void* d_ws, size_t ws_size,
                              hipStream_t stream) {
  const float* g  = (const float*)d_in[0];
  const float* si = (const float*)d_in[1];
  const int*   i1 = (const int*)d_in[2];
  const int*   i2 = (const int*)d_in[3];
  const float* de = (const float*)d_in[4];
  const float* W1 = (const float*)d_in[5];
  const float* b1 = (const float*)d_in[6];
  const float* W2 = (const float*)d_in[7];
  const float* b2 = (const float*)d_in[8];
  const float* W3 = (const float*)d_in[9];
  const float* b3 = (const float*)d_in[10];
  float* out = (float*)d_out;

  char* ws = (char*)d_ws;
  short* g_bf  = (short*)(ws);                 // 1,310,720 B
  short* W1cT  = (short*)(ws + 1310720);       //   204,800 B
  short* W2T   = (short*)(ws + 1515520);       //    61,440 B
  float* U     = (float*)(ws + 1576960);       //   655,360 B
  float* V     = (float*)(ws + 2232320);       //   655,360 B
  float* deW   = (float*)(ws + 2887680);       //     5,760 B
  short* W1abT = (short*)(ws + 2893440);       //   409,600 B  (total ~3.3 MB)

  prep_misc<<<1024, 256, 0, stream>>>(g, W1, W2, de, g_bf, W1cT, W2T, deW, W1abT);
  prep_uv_mfma<<<dim3(16, 2), 256, 0, stream>>>(g_bf, W1abT, b1, U, V);
  pair_main<<<N_PTS, 256, 0, stream>>>(g_bf, W1cT, W2T, U, V, deW, si, i1, i2, W3, b2, b3, out);
}